// Round 9
// baseline (238.095 us; speedup 1.0000x reference)
//
#include <hip/hip_runtime.h>
#include <hip/hip_bf16.h>
#include <stdint.h>
#include <stddef.h>

typedef __bf16 bf16_t;
typedef __bf16 bf16x8 __attribute__((ext_vector_type(8)));
typedef float  f32x4  __attribute__((ext_vector_type(4)));
typedef float  f32x16 __attribute__((ext_vector_type(16)));

#define NN 1024
#define H  128
#define GRID 2048   // 256-thr blocks; 8 consecutive 64-row tiles per block

// ---------------- f_i = node @ Wi^T, f_j = node @ Wj^T (+ fused We->bf16) ----------------
__global__ void k_proj(const float* __restrict__ node,
                       const float* __restrict__ Wi,
                       const float* __restrict__ Wj,
                       const float* __restrict__ We,
                       bf16_t* __restrict__ fi,
                       bf16_t* __restrict__ fj,
                       bf16_t* __restrict__ web) {
    __shared__ float nrow[H];
    const int row = blockIdx.x;
    const int t   = threadIdx.x;
    const int h   = t & (H - 1);
    const int sel = t >> 7;

    // fused We conversion: blocks 0..63 cover all 16384 elements
    if (blockIdx.x < 64) {
        const int i = blockIdx.x * 256 + t;
        web[i] = (bf16_t)We[i];
    }

    if (t < H) nrow[t] = node[(size_t)row * H + t];
    __syncthreads();
    const float* w = (sel ? Wj : Wi) + (size_t)h * H;
    float acc = 0.f;
    #pragma unroll
    for (int k4 = 0; k4 < H / 4; ++k4) {
        f32x4 wv = *(const f32x4*)(w + k4 * 4);
        f32x4 nv = *(const f32x4*)(&nrow[k4 * 4]);
        acc += nv[0] * wv[0] + nv[1] * wv[1] + nv[2] * wv[2] + nv[3] * wv[3];
    }
    bf16_t* dst = sel ? fj : fi;
    dst[(size_t)row * H + h] = (bf16_t)acc;
}

// ---------------- dots[i][j] = f_i[i] . f_j[j]  (grid 128: 16x8 tiles of 64x128) ----------------
__global__ __launch_bounds__(256, 4)
void k_dots(const bf16_t* __restrict__ fi,
            const bf16_t* __restrict__ fj,
            float* __restrict__ dots) {
    const int t    = threadIdx.x;
    const int wave = t >> 6;
    const int lane = t & 63;
    const int l15  = lane & 15;
    const int g    = lane >> 4;

    const int bm    = blockIdx.x >> 3;
    const int bn    = blockIdx.x & 7;
    const int ibase = bm * 64 + wave * 16;
    const int jbase = bn * 128;

    f32x4 acc[8];
    #pragma unroll
    for (int nt = 0; nt < 8; ++nt) acc[nt] = (f32x4){0.f, 0.f, 0.f, 0.f};

    const bf16_t* a = fi + (size_t)(ibase + l15) * H + g * 8;

    #pragma unroll
    for (int kst = 0; kst < 4; ++kst) {
        bf16x8 af = *(const bf16x8*)(a + kst * 32);
        #pragma unroll
        for (int nt = 0; nt < 8; ++nt) {
            bf16x8 bf = *(const bf16x8*)(fj + (size_t)(jbase + nt * 16 + l15) * H + kst * 32 + g * 8);
            acc[nt] = __builtin_amdgcn_mfma_f32_16x16x32_bf16(af, bf, acc[nt], 0, 0, 0);
        }
    }

    const int rbase = ibase + g * 4;
    #pragma unroll
    for (int r = 0; r < 4; ++r)
        #pragma unroll
        for (int nt = 0; nt < 8; ++nt)
            dots[(size_t)(rbase + r) * NN + jbase + nt * 16 + l15] = acc[nt][r];
}

// ---------------- main: out = relu(edge @ We^T + be + dots[row]) ----------------
// R8 control structure, but read path = copy-ubench pattern: global f32x4
// loads -> VGPR (issued at top of iter k for tile k+1, contiguous pre-swizzled
// addresses), ds_write_b128 at END of iteration (after stores) -> loads stay
// in flight across the whole MFMA+store phase; compiler inserts the vmcnt
// before the dependent ds_write. Byte-identical LDS layout to R8, so frag
// reads / MFMA (32x32x16, validated) / full-line stores are unchanged.
// One __syncthreads per iteration.
__global__ __launch_bounds__(256)
void k_main(const float* __restrict__ edge,   // [1M][128] fp32
            const bf16_t* __restrict__ web,   // [128][128] bf16
            const float* __restrict__ be,     // [128]
            const float* __restrict__ dots,   // [1M]
            float* __restrict__ out) {        // [1M][128] fp32
    __shared__ __align__(16) float bufA[64][H];   // 32 KB
    __shared__ __align__(16) float bufB[64][H];   // 32 KB
    __shared__ float ldots[512];

    const int t    = threadIdx.x;       // 0..255
    const int w    = t >> 6;            // wave 0..3
    const int lane = t & 63;
    const int l31  = lane & 31;
    const int h    = lane >> 5;
    const int wm   = w & 1;             // row half of tile
    const int wn   = w >> 1;            // col half of tile
    const size_t base = (size_t)blockIdx.x * 512;   // first edge row of block

    // dots for the block's 512 rows -> LDS
    ldots[t]       = dots[base + t];
    ldots[256 + t] = dots[base + 256 + t];

    // We fragments: B operand, col = wn*64 + nt*32 + l31, k = kk*16 + h*8 + e
    bf16x8 wfr[2][8];
    {
        const bf16_t* wp = web + (size_t)(wn * 64 + l31) * H + h * 8;
        #pragma unroll
        for (int nt = 0; nt < 2; ++nt)
            #pragma unroll
            for (int kk = 0; kk < 8; ++kk)
                wfr[nt][kk] = *(const bf16x8*)(wp + (size_t)(nt * 32) * H + kk * 16);
    }
    float bias[2];
    #pragma unroll
    for (int nt = 0; nt < 2; ++nt) bias[nt] = be[wn * 64 + nt * 32 + l31];

    // reg-staging: wave w covers rows [w*16, w*16+16) of each 64-row tile.
    // Addresses identical to the old gl_lds STAGE (contiguous 1KB per instr,
    // XOR-involution pre-swizzle per row); LDS slots byte-identical too.
    #define LOADT(K, V)                                                          \
        {                                                                        \
            const char* tb = (const char*)(edge + (base + (size_t)(K) * 64) * H); \
            _Pragma("unroll")                                                    \
            for (int i = 0; i < 8; ++i) {                                        \
                const int rr = w * 16 + 2 * i + h;                               \
                V[i] = *(const f32x4*)(tb + rr * 512 + ((l31 * 16) ^ ((rr & 7) << 4))); \
            }                                                                    \
        }
    #define WRITET(BUFP, V)                                                      \
        {                                                                        \
            _Pragma("unroll")                                                    \
            for (int i = 0; i < 8; ++i)                                          \
                *(f32x4*)((char*)&BUFP[w * 16 + 2 * i][0] + h * 512 + l31 * 16) = V[i]; \
        }

    {
        f32x4 v0[8];
        LOADT(0, v0)
        WRITET(bufA, v0)
    }

    const int sw = (l31 & 7) << 4;   // frag-read swizzle (same involution)

    #pragma unroll 1
    for (int k = 0; k < 8; ++k) {
        __syncthreads();   // tile k's ds_writes visible; prior readers done

        // 1) issue next tile's global loads (in flight across MFMA+stores)
        f32x4 vn[8];
        if (k < 7) LOADT(k + 1, vn)

        // 2) fragment reads for tile k: A rows = wm*32 + l31, k = kk*16+h*8+e
        const char* crow = (const char*)((k & 1) ? &bufB[0][0] : &bufA[0][0])
                         + (wm * 32 + l31) * 512;
        f32x4 ua[8], ub[8];
        #pragma unroll
        for (int kk = 0; kk < 8; ++kk) {
            ua[kk] = *(const f32x4*)(crow + ((kk * 64 + h * 32 +  0) ^ sw));
            ub[kk] = *(const f32x4*)(crow + ((kk * 64 + h * 32 + 16) ^ sw));
        }

        // 3) acc init = bias(col) + dots(row); row r = wm*32 + 4h + (reg&3) + 8*(reg>>2)
        f32x4 dv[4];
        #pragma unroll
        for (int b = 0; b < 4; ++b)
            dv[b] = *(const f32x4*)(&ldots[k * 64 + wm * 32 + 4 * h + 8 * b]);

        f32x16 acc[2];
        #pragma unroll
        for (int nt = 0; nt < 2; ++nt)
            #pragma unroll
            for (int r = 0; r < 16; ++r)
                acc[nt][r] = bias[nt] + dv[r >> 2][r & 3];

        #pragma unroll
        for (int kk = 0; kk < 8; ++kk) {
            bf16x8 af;
            #pragma unroll
            for (int e = 0; e < 4; ++e) {
                af[e]     = (bf16_t)ua[kk][e];
                af[e + 4] = (bf16_t)ub[kk][e];
            }
            #pragma unroll
            for (int nt = 0; nt < 2; ++nt)
                acc[nt] = __builtin_amdgcn_mfma_f32_32x32x16_bf16(af, wfr[nt][kk], acc[nt], 0, 0, 0);
        }

        // 4) full-line stores: per (nt,reg) each half-wave writes one 128B line
        float* orow = out + (base + (size_t)k * 64 + wm * 32 + 4 * h) * H + wn * 64 + l31;
        #pragma unroll
        for (int nt = 0; nt < 2; ++nt)
            #pragma unroll
            for (int r = 0; r < 16; ++r)
                orow[((r & 3) + 8 * (r >> 2)) * H + nt * 32] = fmaxf(acc[nt][r], 0.f);

        // 5) drain loads (compiler-inserted vmcnt) + ds_write tile k+1
        if (k < 7) {
            if (k & 1) { WRITET(bufA, vn) }
            else       { WRITET(bufB, vn) }
        }
    }
    #undef LOADT
    #undef WRITET
}

extern "C" void kernel_launch(void* const* d_in, const int* in_sizes, int n_in,
                              void* d_out, int out_size, void* d_ws, size_t ws_size,
                              hipStream_t stream) {
    const float* node = (const float*)d_in[0];
    const float* edge = (const float*)d_in[1];
    const float* We   = (const float*)d_in[2];
    const float* be   = (const float*)d_in[3];
    const float* Wi   = (const float*)d_in[4];
    const float* Wj   = (const float*)d_in[5];
    float* out = (float*)d_out;

    char* w = (char*)d_ws;
    bf16_t* fi_bf = (bf16_t*)w;                              // 256 KB
    bf16_t* fj_bf = (bf16_t*)(w + (256 << 10));              // 256 KB
    float*  dots  = (float*)(w + (512 << 10));               // 4 MB
    bf16_t* web   = (bf16_t*)(w + (512 << 10) + (4 << 20));  // 32 KB

    k_proj<<<NN, 256, 0, stream>>>(node, Wi, Wj, We, fi_bf, fj_bf, web);
    k_dots<<<128, 256, 0, stream>>>(fi_bf, fj_bf, dots);
    k_main<<<GRID, 256, 0, stream>>>(edge, web, be, dots, out);
}

// Round 10
// 235.569 us; speedup vs baseline: 1.0107x; 1.0107x over previous
//
#include <hip/hip_runtime.h>
#include <hip/hip_bf16.h>
#include <stdint.h>
#include <stddef.h>

typedef __bf16 bf16_t;
typedef __bf16 bf16x8 __attribute__((ext_vector_type(8)));
typedef float  f32x4  __attribute__((ext_vector_type(4)));
typedef float  f32x16 __attribute__((ext_vector_type(16)));

#define NN 1024
#define H  128
#define GRID 2048   // 256-thr blocks; 8 consecutive 64-row tiles per block

// ---------------- f_i = node @ Wi^T, f_j = node @ Wj^T (+ fused We->bf16) ----------------
__global__ void k_proj(const float* __restrict__ node,
                       const float* __restrict__ Wi,
                       const float* __restrict__ Wj,
                       const float* __restrict__ We,
                       bf16_t* __restrict__ fi,
                       bf16_t* __restrict__ fj,
                       bf16_t* __restrict__ web) {
    __shared__ float nrow[H];
    const int row = blockIdx.x;
    const int t   = threadIdx.x;
    const int h   = t & (H - 1);
    const int sel = t >> 7;

    // fused We conversion: blocks 0..63 cover all 16384 elements
    if (blockIdx.x < 64) {
        const int i = blockIdx.x * 256 + t;
        web[i] = (bf16_t)We[i];
    }

    if (t < H) nrow[t] = node[(size_t)row * H + t];
    __syncthreads();
    const float* w = (sel ? Wj : Wi) + (size_t)h * H;
    float acc = 0.f;
    #pragma unroll
    for (int k4 = 0; k4 < H / 4; ++k4) {
        f32x4 wv = *(const f32x4*)(w + k4 * 4);
        f32x4 nv = *(const f32x4*)(&nrow[k4 * 4]);
        acc += nv[0] * wv[0] + nv[1] * wv[1] + nv[2] * wv[2] + nv[3] * wv[3];
    }
    bf16_t* dst = sel ? fj : fi;
    dst[(size_t)row * H + h] = (bf16_t)acc;
}

// ---------------- dots[i][j] = f_i[i] . f_j[j]  (grid 128: 16x8 tiles of 64x128) ----------------
__global__ __launch_bounds__(256, 4)
void k_dots(const bf16_t* __restrict__ fi,
            const bf16_t* __restrict__ fj,
            float* __restrict__ dots) {
    const int t    = threadIdx.x;
    const int wave = t >> 6;
    const int lane = t & 63;
    const int l15  = lane & 15;
    const int g    = lane >> 4;

    const int bm    = blockIdx.x >> 3;
    const int bn    = blockIdx.x & 7;
    const int ibase = bm * 64 + wave * 16;
    const int jbase = bn * 128;

    f32x4 acc[8];
    #pragma unroll
    for (int nt = 0; nt < 8; ++nt) acc[nt] = (f32x4){0.f, 0.f, 0.f, 0.f};

    const bf16_t* a = fi + (size_t)(ibase + l15) * H + g * 8;

    #pragma unroll
    for (int kst = 0; kst < 4; ++kst) {
        bf16x8 af = *(const bf16x8*)(a + kst * 32);
        #pragma unroll
        for (int nt = 0; nt < 8; ++nt) {
            bf16x8 bf = *(const bf16x8*)(fj + (size_t)(jbase + nt * 16 + l15) * H + kst * 32 + g * 8);
            acc[nt] = __builtin_amdgcn_mfma_f32_16x16x32_bf16(af, bf, acc[nt], 0, 0, 0);
        }
    }

    const int rbase = ibase + g * 4;
    #pragma unroll
    for (int r = 0; r < 4; ++r)
        #pragma unroll
        for (int nt = 0; nt < 8; ++nt)
            dots[(size_t)(rbase + r) * NN + jbase + nt * 16 + l15] = acc[nt][r];
}

// ---------------- main: out = relu(edge @ We^T + be + dots[row]) ----------------
// R9 structure (reg-staged double buffer, one __syncthreads/iter, 32x32x16
// MFMA, full-line scalar stores) with ONE change: epilogue stores are
// NONTEMPORAL. Each store instruction already covers two full 128B lines
// (32 consecutive lanes x 4B per row), so nt bypasses L2 write-allocate
// without partial-line penalties. Tests the write-allocate-traffic theory
// (true traffic 1.55GB -> already at 6.8 TB/s HW ceiling).
__global__ __launch_bounds__(256)
void k_main(const float* __restrict__ edge,   // [1M][128] fp32
            const bf16_t* __restrict__ web,   // [128][128] bf16
            const float* __restrict__ be,     // [128]
            const float* __restrict__ dots,   // [1M]
            float* __restrict__ out) {        // [1M][128] fp32
    __shared__ __align__(16) float bufA[64][H];   // 32 KB
    __shared__ __align__(16) float bufB[64][H];   // 32 KB
    __shared__ float ldots[512];

    const int t    = threadIdx.x;       // 0..255
    const int w    = t >> 6;            // wave 0..3
    const int lane = t & 63;
    const int l31  = lane & 31;
    const int h    = lane >> 5;
    const int wm   = w & 1;             // row half of tile
    const int wn   = w >> 1;            // col half of tile
    const size_t base = (size_t)blockIdx.x * 512;   // first edge row of block

    // dots for the block's 512 rows -> LDS
    ldots[t]       = dots[base + t];
    ldots[256 + t] = dots[base + 256 + t];

    // We fragments: B operand, col = wn*64 + nt*32 + l31, k = kk*16 + h*8 + e
    bf16x8 wfr[2][8];
    {
        const bf16_t* wp = web + (size_t)(wn * 64 + l31) * H + h * 8;
        #pragma unroll
        for (int nt = 0; nt < 2; ++nt)
            #pragma unroll
            for (int kk = 0; kk < 8; ++kk)
                wfr[nt][kk] = *(const bf16x8*)(wp + (size_t)(nt * 32) * H + kk * 16);
    }
    float bias[2];
    #pragma unroll
    for (int nt = 0; nt < 2; ++nt) bias[nt] = be[wn * 64 + nt * 32 + l31];

    // reg-staging: wave w covers rows [w*16, w*16+16) of each 64-row tile.
    // Contiguous 1KB per wave-instruction, XOR-involution pre-swizzle per row.
    #define LOADT(K, V)                                                          \
        {                                                                        \
            const char* tb = (const char*)(edge + (base + (size_t)(K) * 64) * H); \
            _Pragma("unroll")                                                    \
            for (int i = 0; i < 8; ++i) {                                        \
                const int rr = w * 16 + 2 * i + h;                               \
                V[i] = *(const f32x4*)(tb + rr * 512 + ((l31 * 16) ^ ((rr & 7) << 4))); \
            }                                                                    \
        }
    #define WRITET(BUFP, V)                                                      \
        {                                                                        \
            _Pragma("unroll")                                                    \
            for (int i = 0; i < 8; ++i)                                          \
                *(f32x4*)((char*)&BUFP[w * 16 + 2 * i][0] + h * 512 + l31 * 16) = V[i]; \
        }

    {
        f32x4 v0[8];
        LOADT(0, v0)
        WRITET(bufA, v0)
    }

    const int sw = (l31 & 7) << 4;   // frag-read swizzle (same involution)

    #pragma unroll 1
    for (int k = 0; k < 8; ++k) {
        __syncthreads();   // tile k's ds_writes visible; prior readers done

        // 1) issue next tile's global loads (in flight across MFMA+stores)
        f32x4 vn[8];
        if (k < 7) LOADT(k + 1, vn)

        // 2) fragment reads for tile k: A rows = wm*32 + l31, k = kk*16+h*8+e
        const char* crow = (const char*)((k & 1) ? &bufB[0][0] : &bufA[0][0])
                         + (wm * 32 + l31) * 512;
        f32x4 ua[8], ub[8];
        #pragma unroll
        for (int kk = 0; kk < 8; ++kk) {
            ua[kk] = *(const f32x4*)(crow + ((kk * 64 + h * 32 +  0) ^ sw));
            ub[kk] = *(const f32x4*)(crow + ((kk * 64 + h * 32 + 16) ^ sw));
        }

        // 3) acc init = bias(col) + dots(row); row r = wm*32 + 4h + (reg&3) + 8*(reg>>2)
        f32x4 dv[4];
        #pragma unroll
        for (int b = 0; b < 4; ++b)
            dv[b] = *(const f32x4*)(&ldots[k * 64 + wm * 32 + 4 * h + 8 * b]);

        f32x16 acc[2];
        #pragma unroll
        for (int nt = 0; nt < 2; ++nt)
            #pragma unroll
            for (int r = 0; r < 16; ++r)
                acc[nt][r] = bias[nt] + dv[r >> 2][r & 3];

        #pragma unroll
        for (int kk = 0; kk < 8; ++kk) {
            bf16x8 af;
            #pragma unroll
            for (int e = 0; e < 4; ++e) {
                af[e]     = (bf16_t)ua[kk][e];
                af[e + 4] = (bf16_t)ub[kk][e];
            }
            #pragma unroll
            for (int nt = 0; nt < 2; ++nt)
                acc[nt] = __builtin_amdgcn_mfma_f32_32x32x16_bf16(af, wfr[nt][kk], acc[nt], 0, 0, 0);
        }

        // 4) NONTEMPORAL full-line stores: per (nt,reg) each half-wave writes
        //    one complete 128B line -> nt bypasses L2 write-allocate.
        float* orow = out + (base + (size_t)k * 64 + wm * 32 + 4 * h) * H + wn * 64 + l31;
        #pragma unroll
        for (int nt = 0; nt < 2; ++nt)
            #pragma unroll
            for (int r = 0; r < 16; ++r)
                __builtin_nontemporal_store(
                    fmaxf(acc[nt][r], 0.f),
                    &orow[((r & 3) + 8 * (r >> 2)) * H + nt * 32]);

        // 5) drain loads (compiler-inserted vmcnt) + ds_write tile k+1
        if (k < 7) {
            if (k & 1) { WRITET(bufA, vn) }
            else       { WRITET(bufB, vn) }
        }
    }
    #undef LOADT
    #undef WRITET
}

extern "C" void kernel_launch(void* const* d_in, const int* in_sizes, int n_in,
                              void* d_out, int out_size, void* d_ws, size_t ws_size,
                              hipStream_t stream) {
    const float* node = (const float*)d_in[0];
    const float* edge = (const float*)d_in[1];
    const float* We   = (const float*)d_in[2];
    const float* be   = (const float*)d_in[3];
    const float* Wi   = (const float*)d_in[4];
    const float* Wj   = (const float*)d_in[5];
    float* out = (float*)d_out;

    char* w = (char*)d_ws;
    bf16_t* fi_bf = (bf16_t*)w;                              // 256 KB
    bf16_t* fj_bf = (bf16_t*)(w + (256 << 10));              // 256 KB
    float*  dots  = (float*)(w + (512 << 10));               // 4 MB
    bf16_t* web   = (bf16_t*)(w + (512 << 10) + (4 << 20));  // 32 KB

    k_proj<<<NN, 256, 0, stream>>>(node, Wi, Wj, We, fi_bf, fj_bf, web);
    k_dots<<<128, 256, 0, stream>>>(fi_bf, fj_bf, dots);
    k_main<<<GRID, 256, 0, stream>>>(edge, web, be, dots, out);
}

// Round 11
// 235.307 us; speedup vs baseline: 1.0118x; 1.0011x over previous
//
#include <hip/hip_runtime.h>
#include <hip/hip_bf16.h>
#include <stdint.h>
#include <stddef.h>

typedef __bf16 bf16_t;
typedef __bf16 bf16x8 __attribute__((ext_vector_type(8)));
typedef float  f32x4  __attribute__((ext_vector_type(4)));
typedef float  f32x16 __attribute__((ext_vector_type(16)));

#define NN 1024
#define H  128
#define GRID 2048   // 256-thr blocks; 8 consecutive 64-row tiles per block

// ---------------- f_i = node @ Wi^T, f_j = node @ Wj^T (+ fused We->bf16) ----------------
__global__ void k_proj(const float* __restrict__ node,
                       const float* __restrict__ Wi,
                       const float* __restrict__ Wj,
                       const float* __restrict__ We,
                       bf16_t* __restrict__ fi,
                       bf16_t* __restrict__ fj,
                       bf16_t* __restrict__ web) {
    __shared__ float nrow[H];
    const int row = blockIdx.x;
    const int t   = threadIdx.x;
    const int h   = t & (H - 1);
    const int sel = t >> 7;

    // fused We conversion: blocks 0..63 cover all 16384 elements
    if (blockIdx.x < 64) {
        const int i = blockIdx.x * 256 + t;
        web[i] = (bf16_t)We[i];
    }

    if (t < H) nrow[t] = node[(size_t)row * H + t];
    __syncthreads();
    const float* w = (sel ? Wj : Wi) + (size_t)h * H;
    float acc = 0.f;
    #pragma unroll
    for (int k4 = 0; k4 < H / 4; ++k4) {
        f32x4 wv = *(const f32x4*)(w + k4 * 4);
        f32x4 nv = *(const f32x4*)(&nrow[k4 * 4]);
        acc += nv[0] * wv[0] + nv[1] * wv[1] + nv[2] * wv[2] + nv[3] * wv[3];
    }
    bf16_t* dst = sel ? fj : fi;
    dst[(size_t)row * H + h] = (bf16_t)acc;
}

// ---------------- dots[i][j] = f_i[i] . f_j[j]  (grid 128: 16x8 tiles of 64x128) ----------------
__global__ __launch_bounds__(256, 4)
void k_dots(const bf16_t* __restrict__ fi,
            const bf16_t* __restrict__ fj,
            float* __restrict__ dots) {
    const int t    = threadIdx.x;
    const int wave = t >> 6;
    const int lane = t & 63;
    const int l15  = lane & 15;
    const int g    = lane >> 4;

    const int bm    = blockIdx.x >> 3;
    const int bn    = blockIdx.x & 7;
    const int ibase = bm * 64 + wave * 16;
    const int jbase = bn * 128;

    f32x4 acc[8];
    #pragma unroll
    for (int nt = 0; nt < 8; ++nt) acc[nt] = (f32x4){0.f, 0.f, 0.f, 0.f};

    const bf16_t* a = fi + (size_t)(ibase + l15) * H + g * 8;

    #pragma unroll
    for (int kst = 0; kst < 4; ++kst) {
        bf16x8 af = *(const bf16x8*)(a + kst * 32);
        #pragma unroll
        for (int nt = 0; nt < 8; ++nt) {
            bf16x8 bf = *(const bf16x8*)(fj + (size_t)(jbase + nt * 16 + l15) * H + kst * 32 + g * 8);
            acc[nt] = __builtin_amdgcn_mfma_f32_16x16x32_bf16(af, bf, acc[nt], 0, 0, 0);
        }
    }

    const int rbase = ibase + g * 4;
    #pragma unroll
    for (int r = 0; r < 4; ++r)
        #pragma unroll
        for (int nt = 0; nt < 8; ++nt)
            dots[(size_t)(rbase + r) * NN + jbase + nt * 16 + l15] = acc[nt][r];
}

// ---------------- main: out = relu(edge @ We^T + be + dots[row]) ----------------
// R10 structure with ONE change: the per-iteration __syncthreads (which hipcc
// lowers with a FULL vmcnt(0) drain -- forcing all 32 output stores to retire
// every iteration) is replaced by the raw-barrier pattern:
//   s_waitcnt lgkmcnt(0)  (ds_writes visible cross-wave)
//   s_barrier              (no vmem drain)
// The load->ds_write dependency keeps its compiler-emitted COUNTED vmcnt,
// which leaves the younger stores outstanding. Stores are never waited on.
__global__ __launch_bounds__(256)
void k_main(const float* __restrict__ edge,   // [1M][128] fp32
            const bf16_t* __restrict__ web,   // [128][128] bf16
            const float* __restrict__ be,     // [128]
            const float* __restrict__ dots,   // [1M]
            float* __restrict__ out) {        // [1M][128] fp32
    __shared__ __align__(16) float bufA[64][H];   // 32 KB
    __shared__ __align__(16) float bufB[64][H];   // 32 KB
    __shared__ float ldots[512];

    const int t    = threadIdx.x;       // 0..255
    const int w    = t >> 6;            // wave 0..3
    const int lane = t & 63;
    const int l31  = lane & 31;
    const int h    = lane >> 5;
    const int wm   = w & 1;             // row half of tile
    const int wn   = w >> 1;            // col half of tile
    const size_t base = (size_t)blockIdx.x * 512;   // first edge row of block

    // dots for the block's 512 rows -> LDS
    ldots[t]       = dots[base + t];
    ldots[256 + t] = dots[base + 256 + t];

    // We fragments: B operand, col = wn*64 + nt*32 + l31, k = kk*16 + h*8 + e
    bf16x8 wfr[2][8];
    {
        const bf16_t* wp = web + (size_t)(wn * 64 + l31) * H + h * 8;
        #pragma unroll
        for (int nt = 0; nt < 2; ++nt)
            #pragma unroll
            for (int kk = 0; kk < 8; ++kk)
                wfr[nt][kk] = *(const bf16x8*)(wp + (size_t)(nt * 32) * H + kk * 16);
    }
    float bias[2];
    #pragma unroll
    for (int nt = 0; nt < 2; ++nt) bias[nt] = be[wn * 64 + nt * 32 + l31];

    // reg-staging: wave w covers rows [w*16, w*16+16) of each 64-row tile.
    // Contiguous 1KB per wave-instruction, XOR-involution pre-swizzle per row.
    #define LOADT(K, V)                                                          \
        {                                                                        \
            const char* tb = (const char*)(edge + (base + (size_t)(K) * 64) * H); \
            _Pragma("unroll")                                                    \
            for (int i = 0; i < 8; ++i) {                                        \
                const int rr = w * 16 + 2 * i + h;                               \
                V[i] = *(const f32x4*)(tb + rr * 512 + ((l31 * 16) ^ ((rr & 7) << 4))); \
            }                                                                    \
        }
    #define WRITET(BUFP, V)                                                      \
        {                                                                        \
            _Pragma("unroll")                                                    \
            for (int i = 0; i < 8; ++i)                                          \
                *(f32x4*)((char*)&BUFP[w * 16 + 2 * i][0] + h * 512 + l31 * 16) = V[i]; \
        }

    // raw barrier: LDS visibility only, NO vmem drain
    #define LDS_BARRIER()                                                        \
        {                                                                        \
            __builtin_amdgcn_sched_barrier(0);                                   \
            asm volatile("s_waitcnt lgkmcnt(0)" ::: "memory");                   \
            __builtin_amdgcn_s_barrier();                                        \
            __builtin_amdgcn_sched_barrier(0);                                   \
        }

    {
        f32x4 v0[8];
        LOADT(0, v0)
        WRITET(bufA, v0)
    }

    const int sw = (l31 & 7) << 4;   // frag-read swizzle (same involution)

    #pragma unroll 1
    for (int k = 0; k < 8; ++k) {
        LDS_BARRIER()   // tile k's ds_writes visible; prior readers done

        // 1) issue next tile's global loads (in flight across MFMA+stores)
        f32x4 vn[8];
        if (k < 7) LOADT(k + 1, vn)

        // 2) fragment reads for tile k: A rows = wm*32 + l31, k = kk*16+h*8+e
        const char* crow = (const char*)((k & 1) ? &bufB[0][0] : &bufA[0][0])
                         + (wm * 32 + l31) * 512;
        f32x4 ua[8], ub[8];
        #pragma unroll
        for (int kk = 0; kk < 8; ++kk) {
            ua[kk] = *(const f32x4*)(crow + ((kk * 64 + h * 32 +  0) ^ sw));
            ub[kk] = *(const f32x4*)(crow + ((kk * 64 + h * 32 + 16) ^ sw));
        }

        // 3) acc init = bias(col) + dots(row); row r = wm*32 + 4h + (reg&3) + 8*(reg>>2)
        f32x4 dv[4];
        #pragma unroll
        for (int b = 0; b < 4; ++b)
            dv[b] = *(const f32x4*)(&ldots[k * 64 + wm * 32 + 4 * h + 8 * b]);

        f32x16 acc[2];
        #pragma unroll
        for (int nt = 0; nt < 2; ++nt)
            #pragma unroll
            for (int r = 0; r < 16; ++r)
                acc[nt][r] = bias[nt] + dv[r >> 2][r & 3];

        #pragma unroll
        for (int kk = 0; kk < 8; ++kk) {
            bf16x8 af;
            #pragma unroll
            for (int e = 0; e < 4; ++e) {
                af[e]     = (bf16_t)ua[kk][e];
                af[e + 4] = (bf16_t)ub[kk][e];
            }
            #pragma unroll
            for (int nt = 0; nt < 2; ++nt)
                acc[nt] = __builtin_amdgcn_mfma_f32_32x32x16_bf16(af, wfr[nt][kk], acc[nt], 0, 0, 0);
        }

        // 4) NONTEMPORAL full-line stores: per (nt,reg) each half-wave writes
        //    one complete 128B line; never waited on.
        float* orow = out + (base + (size_t)k * 64 + wm * 32 + 4 * h) * H + wn * 64 + l31;
        #pragma unroll
        for (int nt = 0; nt < 2; ++nt)
            #pragma unroll
            for (int r = 0; r < 16; ++r)
                __builtin_nontemporal_store(
                    fmaxf(acc[nt][r], 0.f),
                    &orow[((r & 3) + 8 * (r >> 2)) * H + nt * 32]);

        // 5) ds_write tile k+1 (compiler emits a COUNTED vmcnt for the vn
        //    dependency -- the 32 younger stores stay outstanding)
        if (k < 7) {
            if (k & 1) { WRITET(bufA, vn) }
            else       { WRITET(bufB, vn) }
        }
    }
    #undef LOADT
    #undef WRITET
    #undef LDS_BARRIER
}

extern "C" void kernel_launch(void* const* d_in, const int* in_sizes, int n_in,
                              void* d_out, int out_size, void* d_ws, size_t ws_size,
                              hipStream_t stream) {
    const float* node = (const float*)d_in[0];
    const float* edge = (const float*)d_in[1];
    const float* We   = (const float*)d_in[2];
    const float* be   = (const float*)d_in[3];
    const float* Wi   = (const float*)d_in[4];
    const float* Wj   = (const float*)d_in[5];
    float* out = (float*)d_out;

    char* w = (char*)d_ws;
    bf16_t* fi_bf = (bf16_t*)w;                              // 256 KB
    bf16_t* fj_bf = (bf16_t*)(w + (256 << 10));              // 256 KB
    float*  dots  = (float*)(w + (512 << 10));               // 4 MB
    bf16_t* web   = (bf16_t*)(w + (512 << 10) + (4 << 20));  // 32 KB

    k_proj<<<NN, 256, 0, stream>>>(node, Wi, Wj, We, fi_bf, fj_bf, web);
    k_dots<<<128, 256, 0, stream>>>(fi_bf, fj_bf, dots);
    k_main<<<GRID, 256, 0, stream>>>(edge, web, be, dots, out);
}